// Round 1
// baseline (309.595 us; speedup 1.0000x reference)
//
#include <hip/hip_runtime.h>
#include <math.h>

#define NB 4
#define NC 64
#define NN 4096
#define MS 16
#define MCHUNK (NN / MS)   // 256
#define TILE 32

// ---------------------------------------------------------------------------
// Kernel 1: Q = Wq*x + bq, K = Wk*x + bk (both [B,N,64] row-major per position),
//           vw[b,n] = (Wo·Wv)·x[b,:,n] + Wo·bv   (V and output proj collapsed)
// ---------------------------------------------------------------------------
__global__ __launch_bounds__(256) void prep_kernel(
    const float* __restrict__ x,
    const float* __restrict__ Wq, const float* __restrict__ bq,
    const float* __restrict__ Wk, const float* __restrict__ bk,
    const float* __restrict__ Wv, const float* __restrict__ bv,
    const float* __restrict__ Wo,
    float* __restrict__ Q, float* __restrict__ K, float* __restrict__ VW)
{
    __shared__ float xt[64][65];   // [c][n], +1 pad
    __shared__ float wve[64];
    const int blk = blockIdx.x;        // NB * (NN/64) blocks
    const int b = blk >> 6;
    const int n0 = (blk & 63) << 6;
    const int tid = threadIdx.x;

    const float* xb = x + (size_t)b * NC * NN;
    for (int idx = tid; idx < 64 * 64; idx += 256) {
        int c = idx >> 6, n = idx & 63;
        xt[c][n] = xb[(size_t)c * NN + n0 + n];
    }
    if (tid < 64) {
        float acc = 0.f;
        for (int e = 0; e < 64; ++e) acc = fmaf(Wo[e], Wv[e * 64 + tid], acc);
        wve[tid] = acc;
    }
    __syncthreads();

    const int nl = tid & 63;           // lane-varying n (coalesced LDS reads)
    const int d0 = (tid >> 6) * 16;    // wave-uniform d block -> scalar Wq/Wk loads
    float qacc[16], kacc[16];
    #pragma unroll
    for (int i = 0; i < 16; ++i) { qacc[i] = bq[d0 + i]; kacc[i] = bk[d0 + i]; }
    for (int c = 0; c < 64; ++c) {
        float xv = xt[c][nl];
        #pragma unroll
        for (int i = 0; i < 16; ++i) {
            qacc[i] = fmaf(Wq[(d0 + i) * 64 + c], xv, qacc[i]);
            kacc[i] = fmaf(Wk[(d0 + i) * 64 + c], xv, kacc[i]);
        }
    }
    size_t base = ((size_t)b * NN + n0 + nl) * 64 + d0;
    #pragma unroll
    for (int i = 0; i < 16; ++i) { Q[base + i] = qacc[i]; K[base + i] = kacc[i]; }

    if (tid < 64) {
        float acc = 0.f;
        for (int c = 0; c < 64; ++c) acc = fmaf(wve[c], xt[c][tid], acc);
        float cv = 0.f;
        for (int e = 0; e < 64; ++e) cv = fmaf(Wo[e], bv[e], cv);
        VW[(size_t)b * NN + n0 + tid] = acc + cv;
    }
}

// ---------------------------------------------------------------------------
// Kernel 2: flash attention over m, split MS ways. One wave per block.
// lane = query (64 queries/block). Online (max, Z, A) with scalar vw weights.
// ---------------------------------------------------------------------------
__global__ __launch_bounds__(64) void attn_partial(
    const float* __restrict__ Q, const float* __restrict__ K,
    const float* __restrict__ VW, float* __restrict__ P)
{
    __shared__ float4 kt[TILE * 16];   // 32 keys x 64 dims
    __shared__ float vwt[TILE];
    const int blk = blockIdx.x;        // NB * (NN/64) * MS
    const int ms = blk & (MS - 1);
    const int t = blk / MS;
    const int b = t >> 6;
    const int n0 = (t & 63) << 6;
    const int lane = threadIdx.x;

    float4 q4[16];
    const float4* qp4 = (const float4*)(Q + ((size_t)b * NN + n0 + lane) * 64);
    #pragma unroll
    for (int i = 0; i < 16; ++i) q4[i] = qp4[i];

    float m = -INFINITY, Zs = 0.f, As = 0.f;
    const int mbase = ms * MCHUNK;
    for (int t0 = 0; t0 < MCHUNK; t0 += TILE) {
        __syncthreads();
        const float4* kp4 = (const float4*)(K + ((size_t)b * NN + mbase + t0) * 64);
        #pragma unroll
        for (int it = 0; it < TILE * 16 / 64; ++it)
            kt[it * 64 + lane] = kp4[it * 64 + lane];
        if (lane < TILE) vwt[lane] = VW[(size_t)b * NN + mbase + t0 + lane];
        __syncthreads();
        #pragma unroll 2
        for (int j = 0; j < TILE; ++j) {
            const float4* kr = &kt[j * 16];      // uniform address -> broadcast
            float s0 = 0.f, s1 = 0.f, s2 = 0.f, s3 = 0.f;
            #pragma unroll
            for (int i = 0; i < 16; ++i) {
                float4 kv = kr[i];
                s0 = fmaf(q4[i].x, kv.x, s0);
                s1 = fmaf(q4[i].y, kv.y, s1);
                s2 = fmaf(q4[i].z, kv.z, s2);
                s3 = fmaf(q4[i].w, kv.w, s3);
            }
            float s = ((s0 + s1) + (s2 + s3)) * 0.125f;   // 1/sqrt(64)
            float nm = fmaxf(m, s);
            float sf = __expf(m - nm);                    // exp(-inf)=0 on 1st iter
            float e  = __expf(s - nm);
            Zs = fmaf(Zs, sf, e);
            As = fmaf(As, sf, e * vwt[j]);
            m = nm;
        }
    }
    size_t pidx = (((size_t)b * NN + n0 + lane) * MS + ms) * 3;
    P[pidx] = m; P[pidx + 1] = Zs; P[pidx + 2] = As;
}

// ---------------------------------------------------------------------------
// Kernel 3: merge MS partials per query, sigmoid(A/Z + bo)
// ---------------------------------------------------------------------------
__global__ __launch_bounds__(256) void combine_kernel(
    const float* __restrict__ P, const float* __restrict__ bo,
    float* __restrict__ out)
{
    int i = blockIdx.x * 256 + threadIdx.x;
    if (i >= NB * NN) return;
    const float* p = P + (size_t)i * MS * 3;
    float M = -INFINITY;
    #pragma unroll
    for (int s = 0; s < MS; ++s) M = fmaxf(M, p[s * 3]);
    float Z = 0.f, A = 0.f;
    #pragma unroll
    for (int s = 0; s < MS; ++s) {
        float sc = __expf(p[s * 3] - M);
        Z = fmaf(p[s * 3 + 1], sc, Z);
        A = fmaf(p[s * 3 + 2], sc, A);
    }
    float y = A / Z + bo[0];
    out[i] = 1.f / (1.f + __expf(-y));
}

extern "C" void kernel_launch(void* const* d_in, const int* in_sizes, int n_in,
                              void* d_out, int out_size, void* d_ws, size_t ws_size,
                              hipStream_t stream)
{
    const float* x  = (const float*)d_in[0];
    const float* Wq = (const float*)d_in[1];
    const float* bq = (const float*)d_in[2];
    const float* Wk = (const float*)d_in[3];
    const float* bk = (const float*)d_in[4];
    const float* Wv = (const float*)d_in[5];
    const float* bv = (const float*)d_in[6];
    const float* Wo = (const float*)d_in[7];
    const float* bo = (const float*)d_in[8];
    float* out = (float*)d_out;

    float* Q  = (float*)d_ws;                  // B*N*64 floats
    float* K  = Q + (size_t)NB * NN * 64;      // B*N*64 floats
    float* VW = K + (size_t)NB * NN * 64;      // B*N floats
    float* P  = VW + (size_t)NB * NN;          // B*N*MS*3 floats (~11.6 MB total)

    prep_kernel<<<NB * (NN / 64), 256, 0, stream>>>(x, Wq, bq, Wk, bk, Wv, bv, Wo, Q, K, VW);
    attn_partial<<<NB * (NN / 64) * MS, 64, 0, stream>>>(Q, K, VW, P);
    combine_kernel<<<(NB * NN + 255) / 256, 256, 0, stream>>>(P, bo, out);
}

// Round 2
// 88.121 us; speedup vs baseline: 3.5133x; 3.5133x over previous
//
#include <hip/hip_runtime.h>
#include <math.h>

#define NB 4
#define NC 64
#define NN 4096
#define KSPLIT 4
#define KCHUNK (NN / KSPLIT)   // 1024 keys per block
#define NT (KCHUNK / 16)       // 64 key-tiles per block

typedef __bf16 bf16x8 __attribute__((ext_vector_type(8)));
typedef float f32x4 __attribute__((ext_vector_type(4)));

static __device__ inline unsigned short f2bf(float f) {
    union { float f; unsigned u; } v; v.f = f;
    unsigned r = v.u + 0x7fffu + ((v.u >> 16) & 1u);   // round-to-nearest-even
    return (unsigned short)(r >> 16);
}

// ---------------------------------------------------------------------------
// Kernel 1: Q,K = W*x + b  -> bf16 [B][N][64] row-major;
//           vw[b,n] = (Wo·Wv)·x[b,:,n] + Wo·bv  (V and 1xC out-proj collapsed)
// ---------------------------------------------------------------------------
__global__ __launch_bounds__(256) void prep_kernel(
    const float* __restrict__ x,
    const float* __restrict__ Wq, const float* __restrict__ bq,
    const float* __restrict__ Wk, const float* __restrict__ bk,
    const float* __restrict__ Wv, const float* __restrict__ bv,
    const float* __restrict__ Wo,
    unsigned short* __restrict__ Qb, unsigned short* __restrict__ Kb,
    float* __restrict__ VW)
{
    __shared__ float xt[64][65];
    __shared__ float wve[64];
    const int blk = blockIdx.x;        // NB * (NN/64)
    const int b = blk >> 6;
    const int n0 = (blk & 63) << 6;
    const int tid = threadIdx.x;

    const float* xb = x + (size_t)b * NC * NN;
    for (int idx = tid; idx < 64 * 64; idx += 256) {
        int c = idx >> 6, n = idx & 63;
        xt[c][n] = xb[(size_t)c * NN + n0 + n];
    }
    if (tid < 64) {
        float acc = 0.f;
        for (int e = 0; e < 64; ++e) acc = fmaf(Wo[e], Wv[e * 64 + tid], acc);
        wve[tid] = acc;
    }
    __syncthreads();

    const int nl = tid & 63;
    const int d0 = (tid >> 6) * 16;
    float qacc[16], kacc[16];
    #pragma unroll
    for (int i = 0; i < 16; ++i) { qacc[i] = bq[d0 + i]; kacc[i] = bk[d0 + i]; }
    for (int c = 0; c < 64; ++c) {
        float xv = xt[c][nl];
        #pragma unroll
        for (int i = 0; i < 16; ++i) {
            qacc[i] = fmaf(Wq[(d0 + i) * 64 + c], xv, qacc[i]);
            kacc[i] = fmaf(Wk[(d0 + i) * 64 + c], xv, kacc[i]);
        }
    }
    // pack 16 bf16 -> two 16B stores each for Q and K
    union { unsigned short u[8]; uint4 v; } pk;
    size_t base = ((size_t)b * NN + n0 + nl) * 64 + d0;
    #pragma unroll
    for (int h = 0; h < 2; ++h) {
        #pragma unroll
        for (int i = 0; i < 8; ++i) pk.u[i] = f2bf(qacc[h * 8 + i]);
        *(uint4*)(Qb + base + h * 8) = pk.v;
    }
    #pragma unroll
    for (int h = 0; h < 2; ++h) {
        #pragma unroll
        for (int i = 0; i < 8; ++i) pk.u[i] = f2bf(kacc[h * 8 + i]);
        *(uint4*)(Kb + base + h * 8) = pk.v;
    }

    if (tid < 64) {
        float acc = 0.f;
        for (int c = 0; c < 64; ++c) acc = fmaf(wve[c], xt[c][tid], acc);
        float cv = 0.f;
        for (int e = 0; e < 64; ++e) cv = fmaf(Wo[e], bv[e], cv);
        VW[(size_t)b * NN + n0 + tid] = acc + cv;
    }
}

// ---------------------------------------------------------------------------
// Kernel 2: MFMA flash attention. Swapped QK^T: S^T = K·Q^T via
// mfma_f32_16x16x32_bf16 (A = 16-key tile, B = Q^T). Lane owns query
// (lane&15) and 4 keys per tile; per-lane online (m,Z,A) in log2 domain;
// merged across lane-groups with shfl_xor at the end. KSPLIT for occupancy.
// ---------------------------------------------------------------------------
__global__ __launch_bounds__(256) void attn_mfma(
    const unsigned short* __restrict__ Qb, const unsigned short* __restrict__ Kb,
    const float* __restrict__ VW, float* __restrict__ P)
{
    __shared__ float vws[KCHUNK];      // 4 KB
    const int blk = blockIdx.x;        // NB * (NN/64) * KSPLIT
    const int ks = blk & (KSPLIT - 1);
    const int t = blk / KSPLIT;
    const int b = t >> 6;
    const int q0 = (t & 63) << 6;
    const int tid = threadIdx.x;
    const int wid = tid >> 6, lane = tid & 63;
    const int lg = lane >> 4;          // lane group 0..3
    const int ll = lane & 15;

    const int kbase = ks * KCHUNK;
    for (int i = tid; i < KCHUNK; i += 256) vws[i] = VW[(size_t)b * NN + kbase + i];
    __syncthreads();

    // Q fragment (B operand): query = q0 + wid*16 + ll, dims lg*8..+8 (+32)
    const int qrow = q0 + wid * 16 + ll;
    const unsigned short* qp = Qb + ((size_t)b * NN + qrow) * 64 + lg * 8;
    const bf16x8 qf0 = *(const bf16x8*)(qp);
    const bf16x8 qf1 = *(const bf16x8*)(qp + 32);

    // K fragment (A operand): key row = tile + ll, dims lg*8..+8 (+32)
    const unsigned short* kp = Kb + ((size_t)b * NN + kbase + ll) * 64 + lg * 8;

    const float C = 0.125f * 1.44269504f;  // 1/sqrt(64) * log2(e)
    float m = -INFINITY, Zs = 0.f, As = 0.f;

    bf16x8 ka0 = *(const bf16x8*)(kp);
    bf16x8 ka1 = *(const bf16x8*)(kp + 32);

    #pragma unroll 2
    for (int kt = 0; kt < NT; ++kt) {
        const bf16x8 ca0 = ka0, ca1 = ka1;
        const int nx = (kt + 1 < NT) ? (kt + 1) : kt;      // clamp (1 dup load)
        const unsigned short* np = kp + (size_t)nx * (16 * 64);
        ka0 = *(const bf16x8*)(np);
        ka1 = *(const bf16x8*)(np + 32);

        f32x4 acc = {0.f, 0.f, 0.f, 0.f};
        acc = __builtin_amdgcn_mfma_f32_16x16x32_bf16(ca0, qf0, acc, 0, 0, 0);
        acc = __builtin_amdgcn_mfma_f32_16x16x32_bf16(ca1, qf1, acc, 0, 0, 0);

        const float4 vv = *(const float4*)&vws[kt * 16 + lg * 4];
        float s0 = acc[0] * C, s1 = acc[1] * C, s2 = acc[2] * C, s3 = acc[3] * C;
        float pmax = fmaxf(fmaxf(s0, s1), fmaxf(s2, s3));
        float nm = fmaxf(m, pmax);
        float sf = exp2f(m - nm);                 // 0 on first tile (m=-inf)
        float e0 = exp2f(s0 - nm), e1 = exp2f(s1 - nm);
        float e2 = exp2f(s2 - nm), e3 = exp2f(s3 - nm);
        Zs = fmaf(Zs, sf, (e0 + e1) + (e2 + e3));
        As = fmaf(As, sf, fmaf(e0, vv.x, fmaf(e1, vv.y, fmaf(e2, vv.z, e3 * vv.w))));
        m = nm;
    }

    // merge the 4 lane-groups holding the same query
    #pragma unroll
    for (int off = 16; off < 64; off <<= 1) {
        float mo = __shfl_xor(m, off);
        float Zo = __shfl_xor(Zs, off);
        float Ao = __shfl_xor(As, off);
        float nm = fmaxf(m, mo);
        float sa = exp2f(m - nm), sb = exp2f(mo - nm);
        Zs = Zs * sa + Zo * sb;
        As = As * sa + Ao * sb;
        m = nm;
    }

    if (lg == 0) {
        size_t pi = (((size_t)b * NN + qrow) * KSPLIT + ks) * 3;
        P[pi] = m; P[pi + 1] = Zs; P[pi + 2] = As;
    }
}

// ---------------------------------------------------------------------------
// Kernel 3: merge KSPLIT partials per query, sigmoid(A/Z + bo)
// ---------------------------------------------------------------------------
__global__ __launch_bounds__(256) void combine_kernel(
    const float* __restrict__ P, const float* __restrict__ bo,
    float* __restrict__ out)
{
    int i = blockIdx.x * 256 + threadIdx.x;
    if (i >= NB * NN) return;
    const float* p = P + (size_t)i * KSPLIT * 3;
    float M = -INFINITY;
    #pragma unroll
    for (int s = 0; s < KSPLIT; ++s) M = fmaxf(M, p[s * 3]);
    float Z = 0.f, A = 0.f;
    #pragma unroll
    for (int s = 0; s < KSPLIT; ++s) {
        float sc = exp2f(p[s * 3] - M);
        Z = fmaf(p[s * 3 + 1], sc, Z);
        A = fmaf(p[s * 3 + 2], sc, A);
    }
    float y = A / Z + bo[0];
    out[i] = 1.f / (1.f + __expf(-y));
}

extern "C" void kernel_launch(void* const* d_in, const int* in_sizes, int n_in,
                              void* d_out, int out_size, void* d_ws, size_t ws_size,
                              hipStream_t stream)
{
    const float* x  = (const float*)d_in[0];
    const float* Wq = (const float*)d_in[1];
    const float* bq = (const float*)d_in[2];
    const float* Wk = (const float*)d_in[3];
    const float* bk = (const float*)d_in[4];
    const float* Wv = (const float*)d_in[5];
    const float* bv = (const float*)d_in[6];
    const float* Wo = (const float*)d_in[7];
    const float* bo = (const float*)d_in[8];
    float* out = (float*)d_out;

    unsigned short* Qb = (unsigned short*)d_ws;                  // B*N*64 bf16
    unsigned short* Kb = Qb + (size_t)NB * NN * 64;              // B*N*64 bf16
    float* VW = (float*)(Kb + (size_t)NB * NN * 64);             // B*N f32
    float* P  = VW + (size_t)NB * NN;                            // B*N*KSPLIT*3 f32

    prep_kernel<<<NB * (NN / 64), 256, 0, stream>>>(x, Wq, bq, Wk, bk, Wv, bv, Wo, Qb, Kb, VW);
    attn_mfma<<<NB * (NN / 64) * KSPLIT, 256, 0, stream>>>(Qb, Kb, VW, P);
    combine_kernel<<<(NB * NN + 255) / 256, 256, 0, stream>>>(P, bo, out);
}

// Round 3
// 70.299 us; speedup vs baseline: 4.4040x; 1.2535x over previous
//
#include <hip/hip_runtime.h>
#include <math.h>

#define NB 4
#define NN 4096
#define KS 8                  // key-split: blocks per q-block
#define KPB 512               // keys per block (NN/KS)
#define KPW 128               // keys per wave
#define NTILES 8              // KPW / 16
#define QSCALE 0.1803368801f  // (1/sqrt(64)) * log2(e) -> scores in log2 domain

typedef __bf16 bf16x8 __attribute__((ext_vector_type(8)));
typedef float f32x4 __attribute__((ext_vector_type(4)));

static __device__ inline unsigned short f2bf(float f) {
    union { float f; unsigned u; } v; v.f = f;
    unsigned r = v.u + 0x7fffu + ((v.u >> 16) & 1u);   // RNE
    return (unsigned short)(r >> 16);
}

// ---------------------------------------------------------------------------
// Kernel 1: one projection per block (proj=0: Q*QSCALE + VW, proj=1: K).
// Q,K -> bf16 [B][N][64]; vw[b,n] = (Wo·Wv)·x[b,:,n] + Wo·bv
// ---------------------------------------------------------------------------
__global__ __launch_bounds__(256) void prep_kernel(
    const float* __restrict__ x,
    const float* __restrict__ Wq, const float* __restrict__ bq,
    const float* __restrict__ Wk, const float* __restrict__ bk,
    const float* __restrict__ Wv, const float* __restrict__ bv,
    const float* __restrict__ Wo,
    unsigned short* __restrict__ Qb, unsigned short* __restrict__ Kb,
    float* __restrict__ VW)
{
    __shared__ float xt[64][65];
    __shared__ float wve[64];
    const int blk = blockIdx.x;        // NB*64*2
    const int proj = blk & 1;
    const int t = blk >> 1;
    const int b = t >> 6;
    const int n0 = (t & 63) << 6;
    const int tid = threadIdx.x;

    const float* xb = x + (size_t)b * 64 * NN;
    for (int idx = tid; idx < 64 * 64; idx += 256) {
        int c = idx >> 6, n = idx & 63;
        xt[c][n] = xb[(size_t)c * NN + n0 + n];
    }
    if (proj == 0 && tid < 64) {
        float a = 0.f;
        for (int e = 0; e < 64; ++e) a = fmaf(Wo[e], Wv[e * 64 + tid], a);
        wve[tid] = a;
    }
    __syncthreads();

    const float* W  = proj ? Wk : Wq;
    const float* bs = proj ? bk : bq;
    unsigned short* Out = proj ? Kb : Qb;
    const int nl = tid & 63;
    const int d0 = (tid >> 6) << 4;
    float acc[16];
    #pragma unroll
    for (int i = 0; i < 16; ++i) acc[i] = bs[d0 + i];
    for (int c = 0; c < 64; ++c) {
        float xv = xt[c][nl];
        #pragma unroll
        for (int i = 0; i < 16; ++i)
            acc[i] = fmaf(W[(d0 + i) * 64 + c], xv, acc[i]);
    }
    if (proj == 0) {
        #pragma unroll
        for (int i = 0; i < 16; ++i) acc[i] *= QSCALE;
    }
    union { unsigned short u[8]; uint4 v; } pk;
    size_t base = ((size_t)b * NN + n0 + nl) * 64 + d0;
    #pragma unroll
    for (int h = 0; h < 2; ++h) {
        #pragma unroll
        for (int i = 0; i < 8; ++i) pk.u[i] = f2bf(acc[h * 8 + i]);
        *(uint4*)(Out + base + h * 8) = pk.v;
    }

    if (proj == 0 && tid < 64) {
        float a = 0.f;
        for (int c = 0; c < 64; ++c) a = fmaf(wve[c], xt[c][tid], a);
        float cv = 0.f;
        for (int e = 0; e < 64; ++e) cv = fmaf(Wo[e], bv[e], cv);
        VW[(size_t)b * NN + n0 + tid] = a + cv;
    }
}

// ---------------------------------------------------------------------------
// Kernel 2: MFMA attention, no max-tracking (scores pre-scaled to log2 domain,
// bounded; softmax is shift-invariant). Swapped QK^T: lane owns 4 keys x
// query(ll), 4 q-groups per wave share every K fragment. Pure-add partials.
// ---------------------------------------------------------------------------
__global__ __launch_bounds__(256) void attn_mfma(
    const unsigned short* __restrict__ Qb, const unsigned short* __restrict__ Kb,
    const float* __restrict__ VW, float2* __restrict__ P2)
{
    __shared__ float vws[KPB];
    const int blk = blockIdx.x;        // ((b*64 + qb)*KS + ks)
    const int ks = blk & (KS - 1);
    const int t = blk >> 3;
    const int b = t >> 6;
    const int q0 = (t & 63) << 6;
    const int tid = threadIdx.x;
    const int wid = tid >> 6;
    const int lane = tid & 63;
    const int lg = lane >> 4, ll = lane & 15;

    for (int i = tid; i < KPB; i += 256)
        vws[i] = VW[(size_t)b * NN + ks * KPB + i];
    __syncthreads();

    bf16x8 qfa[4], qfb[4];
    #pragma unroll
    for (int g = 0; g < 4; ++g) {
        const unsigned short* qp = Qb + ((size_t)b * NN + q0 + g * 16 + ll) * 64 + lg * 8;
        qfa[g] = *(const bf16x8*)qp;
        qfb[g] = *(const bf16x8*)(qp + 32);
    }
    const unsigned short* kp =
        Kb + ((size_t)b * NN + ks * KPB + wid * KPW + ll) * 64 + lg * 8;

    float Zg[4] = {0.f, 0.f, 0.f, 0.f};
    float Ag[4] = {0.f, 0.f, 0.f, 0.f};
    bf16x8 ka0 = *(const bf16x8*)kp;
    bf16x8 ka1 = *(const bf16x8*)(kp + 32);

    #pragma unroll
    for (int kt = 0; kt < NTILES; ++kt) {
        const bf16x8 ca0 = ka0, ca1 = ka1;
        const int nx = (kt + 1 < NTILES) ? kt + 1 : kt;
        const unsigned short* np = kp + (size_t)nx * (16 * 64);
        ka0 = *(const bf16x8*)np;
        ka1 = *(const bf16x8*)(np + 32);

        const float4 vv = *(const float4*)&vws[wid * KPW + kt * 16 + lg * 4];
        #pragma unroll
        for (int g = 0; g < 4; ++g) {
            f32x4 acc = {0.f, 0.f, 0.f, 0.f};
            acc = __builtin_amdgcn_mfma_f32_16x16x32_bf16(ca0, qfa[g], acc, 0, 0, 0);
            acc = __builtin_amdgcn_mfma_f32_16x16x32_bf16(ca1, qfb[g], acc, 0, 0, 0);
            float e0 = __builtin_amdgcn_exp2f(acc[0]);
            float e1 = __builtin_amdgcn_exp2f(acc[1]);
            float e2 = __builtin_amdgcn_exp2f(acc[2]);
            float e3 = __builtin_amdgcn_exp2f(acc[3]);
            Zg[g] += (e0 + e1) + (e2 + e3);
            Ag[g] += fmaf(e0, vv.x, fmaf(e1, vv.y, fmaf(e2, vv.z, e3 * vv.w)));
        }
    }

    #pragma unroll
    for (int g = 0; g < 4; ++g) {
        Zg[g] += __shfl_xor(Zg[g], 16);
        Zg[g] += __shfl_xor(Zg[g], 32);
        Ag[g] += __shfl_xor(Ag[g], 16);
        Ag[g] += __shfl_xor(Ag[g], 32);
    }
    float Zo = (lg == 0) ? Zg[0] : (lg == 1) ? Zg[1] : (lg == 2) ? Zg[2] : Zg[3];
    float Ao = (lg == 0) ? Ag[0] : (lg == 1) ? Ag[1] : (lg == 2) ? Ag[2] : Ag[3];
    const int r = ks * 4 + wid;                 // 0..31
    const int q = q0 + lane;                    // lg*16 + ll == lane
    P2[((size_t)r << 14) + ((size_t)b << 12) + q] = make_float2(Zo, Ao);
}

// ---------------------------------------------------------------------------
// Kernel 3: sum 32 additive partials, sigmoid(A/Z + bo)
// ---------------------------------------------------------------------------
__global__ __launch_bounds__(256) void combine_kernel(
    const float2* __restrict__ P2, const float* __restrict__ bo,
    float* __restrict__ out)
{
    int i = blockIdx.x * 256 + threadIdx.x;     // NB*NN = 16384
    float Z = 0.f, A = 0.f;
    #pragma unroll
    for (int r = 0; r < 32; ++r) {
        float2 p = P2[((size_t)r << 14) + i];
        Z += p.x; A += p.y;
    }
    float y = A / Z + bo[0];
    out[i] = 1.f / (1.f + __expf(-y));
}

extern "C" void kernel_launch(void* const* d_in, const int* in_sizes, int n_in,
                              void* d_out, int out_size, void* d_ws, size_t ws_size,
                              hipStream_t stream)
{
    const float* x  = (const float*)d_in[0];
    const float* Wq = (const float*)d_in[1];
    const float* bq = (const float*)d_in[2];
    const float* Wk = (const float*)d_in[3];
    const float* bk = (const float*)d_in[4];
    const float* Wv = (const float*)d_in[5];
    const float* bv = (const float*)d_in[6];
    const float* Wo = (const float*)d_in[7];
    const float* bo = (const float*)d_in[8];
    float* out = (float*)d_out;

    unsigned short* Qb = (unsigned short*)d_ws;            // B*N*64 bf16 (2 MB)
    unsigned short* Kb = Qb + (size_t)NB * NN * 64;        // 2 MB
    float* VW = (float*)(Kb + (size_t)NB * NN * 64);       // 64 KB
    float2* P2 = (float2*)(VW + (size_t)NB * NN);          // 32*B*N float2 (4 MB)

    prep_kernel<<<NB * 64 * 2, 256, 0, stream>>>(x, Wq, bq, Wk, bk, Wv, bv, Wo, Qb, Kb, VW);
    attn_mfma<<<NB * 64 * KS, 256, 0, stream>>>(Qb, Kb, VW, P2);
    combine_kernel<<<(NB * NN) / 256, 256, 0, stream>>>(P2, bo, out);
}

// Round 4
// 39.970 us; speedup vs baseline: 7.7457x; 1.7588x over previous
//
#include <hip/hip_runtime.h>
#include <math.h>

#define NB 4
#define NN 4096
#define QSCALE 0.1803368801f   // (1/sqrt(64)) * log2(e): scores in log2 domain

#define KS 8                   // key splits
#define KPB 512                // keys per block
#define KPW 128                // keys per wave
#define NTILES 8               // KPW/16
#define NG 8                   // q-groups (16 queries each) per wave

typedef __bf16 bf16x8 __attribute__((ext_vector_type(8)));
typedef float f32x4 __attribute__((ext_vector_type(4)));

union BF8 { unsigned short u[8]; bf16x8 v; uint4 q; };

static __device__ inline unsigned short f2bf(float f) {
    union { float f; unsigned u; } v; v.f = f;
    unsigned r = v.u + 0x7fffu + ((v.u >> 16) & 1u);   // RNE
    return (unsigned short)(r >> 16);
}

// ---------------------------------------------------------------------------
// Kernel 1 (MFMA prep): Qb = bf16((Wq x + bq)*QSCALE) rows [B][N][64],
// Kb = bf16(Wk x + bk), VW[b,n] = (Wo·Wv)·x[:,n] + Wo·bv (fp32).
// Block: 64 positions (4 waves x 16 rows). A-frags from LDS x-tile,
// B-frags = W rows (contiguous). Epilogue transposes via LDS overlay.
// ---------------------------------------------------------------------------
__global__ __launch_bounds__(256) void prep_mfma(
    const float* __restrict__ x,
    const float* __restrict__ Wq, const float* __restrict__ bq,
    const float* __restrict__ Wk, const float* __restrict__ bk,
    const float* __restrict__ Wv, const float* __restrict__ bv,
    const float* __restrict__ Wo,
    unsigned short* __restrict__ Qb, unsigned short* __restrict__ Kb,
    float* __restrict__ VW)
{
    __shared__ float xt[64 * 65];          // 16640 B; overlaid as bf16 rows later
    __shared__ float wve_s[64];
    unsigned short* rows = (unsigned short*)xt;   // [64][72] bf16 staging

    const int blk = blockIdx.x;            // NB*64
    const int b = blk >> 6;
    const int n0 = (blk & 63) << 6;
    const int tid = threadIdx.x;
    const int wid = tid >> 6, lane = tid & 63;
    const int lg = lane >> 4, ll = lane & 15;

    const float* xb = x + (size_t)b * 64 * NN;
    #pragma unroll
    for (int it = 0; it < 16; ++it) {
        int idx = it * 256 + tid;
        int c = idx >> 6, n = idx & 63;
        xt[c * 65 + n] = xb[(size_t)c * NN + n0 + n];
    }
    if (tid < 64) {
        float a = 0.f;
        for (int e = 0; e < 64; ++e) a = fmaf(Wo[e], Wv[e * 64 + tid], a);
        wve_s[tid] = a;
    }
    float cv = 0.f;                         // Wo·bv (scalar chain, overlaps loads)
    for (int e = 0; e < 64; ++e) cv = fmaf(Wo[e], bv[e], cv);
    __syncthreads();

    // A fragments: rows n = wid*16 + ll, k-dim = c
    BF8 a0, a1;
    #pragma unroll
    for (int j = 0; j < 8; ++j) {
        a0.v[j] = (__bf16)xt[(lg * 8 + j) * 65 + wid * 16 + ll];
        a1.v[j] = (__bf16)xt[(32 + lg * 8 + j) * 65 + wid * 16 + ll];
    }

    // VW (fp32): 4 lanes per n, 16 c each, shfl-reduce
    {
        int nrel = wid * 16 + (lane >> 2);
        int part = lane & 3;
        float a = 0.f;
        #pragma unroll
        for (int j = 0; j < 16; ++j)
            a = fmaf(wve_s[part * 16 + j], xt[(part * 16 + j) * 65 + nrel], a);
        a += __shfl_xor(a, 1);
        a += __shfl_xor(a, 2);
        if (part == 0) VW[(size_t)b * NN + n0 + nrel] = a + cv;
    }

    // ---- Q projection: 4 c-tiles x (2 MFMA over K=64) ----
    f32x4 qacc[4];
    #pragma unroll
    for (int ct = 0; ct < 4; ++ct) {
        const float* wr = Wq + (ct * 16 + ll) * 64;
        float4 f0 = *(const float4*)(wr + lg * 8);
        float4 f1 = *(const float4*)(wr + lg * 8 + 4);
        float4 f2 = *(const float4*)(wr + 32 + lg * 8);
        float4 f3 = *(const float4*)(wr + 32 + lg * 8 + 4);
        BF8 w0, w1;
        w0.v[0] = (__bf16)f0.x; w0.v[1] = (__bf16)f0.y; w0.v[2] = (__bf16)f0.z; w0.v[3] = (__bf16)f0.w;
        w0.v[4] = (__bf16)f1.x; w0.v[5] = (__bf16)f1.y; w0.v[6] = (__bf16)f1.z; w0.v[7] = (__bf16)f1.w;
        w1.v[0] = (__bf16)f2.x; w1.v[1] = (__bf16)f2.y; w1.v[2] = (__bf16)f2.z; w1.v[3] = (__bf16)f2.w;
        w1.v[4] = (__bf16)f3.x; w1.v[5] = (__bf16)f3.y; w1.v[6] = (__bf16)f3.z; w1.v[7] = (__bf16)f3.w;
        f32x4 acc = {0.f, 0.f, 0.f, 0.f};
        acc = __builtin_amdgcn_mfma_f32_16x16x32_bf16(a0.v, w0.v, acc, 0, 0, 0);
        acc = __builtin_amdgcn_mfma_f32_16x16x32_bf16(a1.v, w1.v, acc, 0, 0, 0);
        qacc[ct] = acc;
    }
    __syncthreads();   // all xt reads done -> safe to overlay

    // write Q rows (bias + scale), lane holds d = ct*16+ll for 4 n
    #pragma unroll
    for (int ct = 0; ct < 4; ++ct) {
        float bias = bq[ct * 16 + ll];
        #pragma unroll
        for (int r = 0; r < 4; ++r) {
            int n = wid * 16 + lg * 4 + r;
            rows[n * 72 + ct * 16 + ll] = f2bf((qacc[ct][r] + bias) * QSCALE);
        }
    }
    __syncthreads();
    {
        int n = tid >> 2, qq = tid & 3;
        const uint4* src = (const uint4*)&rows[n * 72 + qq * 16];
        uint4 v0 = src[0], v1 = src[1];
        uint4* dst = (uint4*)(Qb + ((size_t)b * NN + n0 + n) * 64 + qq * 16);
        dst[0] = v0; dst[1] = v1;
    }

    // ---- K projection ----
    f32x4 kacc[4];
    #pragma unroll
    for (int ct = 0; ct < 4; ++ct) {
        const float* wr = Wk + (ct * 16 + ll) * 64;
        float4 f0 = *(const float4*)(wr + lg * 8);
        float4 f1 = *(const float4*)(wr + lg * 8 + 4);
        float4 f2 = *(const float4*)(wr + 32 + lg * 8);
        float4 f3 = *(const float4*)(wr + 32 + lg * 8 + 4);
        BF8 w0, w1;
        w0.v[0] = (__bf16)f0.x; w0.v[1] = (__bf16)f0.y; w0.v[2] = (__bf16)f0.z; w0.v[3] = (__bf16)f0.w;
        w0.v[4] = (__bf16)f1.x; w0.v[5] = (__bf16)f1.y; w0.v[6] = (__bf16)f1.z; w0.v[7] = (__bf16)f1.w;
        w1.v[0] = (__bf16)f2.x; w1.v[1] = (__bf16)f2.y; w1.v[2] = (__bf16)f2.z; w1.v[3] = (__bf16)f2.w;
        w1.v[4] = (__bf16)f3.x; w1.v[5] = (__bf16)f3.y; w1.v[6] = (__bf16)f3.z; w1.v[7] = (__bf16)f3.w;
        f32x4 acc = {0.f, 0.f, 0.f, 0.f};
        acc = __builtin_amdgcn_mfma_f32_16x16x32_bf16(a0.v, w0.v, acc, 0, 0, 0);
        acc = __builtin_amdgcn_mfma_f32_16x16x32_bf16(a1.v, w1.v, acc, 0, 0, 0);
        kacc[ct] = acc;
    }
    __syncthreads();   // Q readback done -> safe to overwrite rows
    #pragma unroll
    for (int ct = 0; ct < 4; ++ct) {
        float bias = bk[ct * 16 + ll];
        #pragma unroll
        for (int r = 0; r < 4; ++r) {
            int n = wid * 16 + lg * 4 + r;
            rows[n * 72 + ct * 16 + ll] = f2bf(kacc[ct][r] + bias);
        }
    }
    __syncthreads();
    {
        int n = tid >> 2, qq = tid & 3;
        const uint4* src = (const uint4*)&rows[n * 72 + qq * 16];
        uint4 v0 = src[0], v1 = src[1];
        uint4* dst = (uint4*)(Kb + ((size_t)b * NN + n0 + n) * 64 + qq * 16);
        dst[0] = v0; dst[1] = v1;
    }
}

// ---------------------------------------------------------------------------
// Kernel 2: MFMA attention, no max-tracking (scores bounded, log2 domain).
// 8 q-groups per wave share each K fragment; per-lane additive (Z,A).
// ---------------------------------------------------------------------------
__global__ __launch_bounds__(256) void attn_mfma(
    const unsigned short* __restrict__ Qb, const unsigned short* __restrict__ Kb,
    const float* __restrict__ VW, float2* __restrict__ P2)
{
    __shared__ float vws[KPB];
    const int blk = blockIdx.x;            // ((b*32 + qb)*KS + ks)
    const int ks = blk & (KS - 1);
    const int t = blk >> 3;
    const int b = t >> 5;
    const int q0 = (t & 31) << 7;          // 128-query tile
    const int tid = threadIdx.x;
    const int wid = tid >> 6, lane = tid & 63;
    const int lg = lane >> 4, ll = lane & 15;

    for (int i = tid; i < KPB; i += 256)
        vws[i] = VW[(size_t)b * NN + ks * KPB + i];
    __syncthreads();

    bf16x8 qfa[NG], qfb[NG];
    #pragma unroll
    for (int g = 0; g < NG; ++g) {
        const unsigned short* qp = Qb + ((size_t)b * NN + q0 + g * 16 + ll) * 64 + lg * 8;
        qfa[g] = *(const bf16x8*)qp;
        qfb[g] = *(const bf16x8*)(qp + 32);
    }
    const unsigned short* kp =
        Kb + ((size_t)b * NN + ks * KPB + wid * KPW + ll) * 64 + lg * 8;

    float Zg[NG], Ag[NG];
    #pragma unroll
    for (int g = 0; g < NG; ++g) { Zg[g] = 0.f; Ag[g] = 0.f; }

    bf16x8 ka0 = *(const bf16x8*)kp;
    bf16x8 ka1 = *(const bf16x8*)(kp + 32);

    #pragma unroll
    for (int kt = 0; kt < NTILES; ++kt) {
        const bf16x8 c0 = ka0, c1 = ka1;
        const int nx = (kt + 1 < NTILES) ? kt + 1 : kt;
        const unsigned short* np = kp + (size_t)nx * (16 * 64);
        ka0 = *(const bf16x8*)np;
        ka1 = *(const bf16x8*)(np + 32);

        const float4 vv = *(const float4*)&vws[wid * KPW + kt * 16 + lg * 4];
        #pragma unroll
        for (int g = 0; g < NG; ++g) {
            f32x4 acc = {0.f, 0.f, 0.f, 0.f};
            acc = __builtin_amdgcn_mfma_f32_16x16x32_bf16(c0, qfa[g], acc, 0, 0, 0);
            acc = __builtin_amdgcn_mfma_f32_16x16x32_bf16(c1, qfb[g], acc, 0, 0, 0);
            float e0 = __builtin_amdgcn_exp2f(acc[0]);
            float e1 = __builtin_amdgcn_exp2f(acc[1]);
            float e2 = __builtin_amdgcn_exp2f(acc[2]);
            float e3 = __builtin_amdgcn_exp2f(acc[3]);
            Zg[g] += (e0 + e1) + (e2 + e3);
            Ag[g] += fmaf(e0, vv.x, fmaf(e1, vv.y, fmaf(e2, vv.z, e3 * vv.w)));
        }
    }

    #pragma unroll
    for (int g = 0; g < NG; ++g) {
        Zg[g] += __shfl_xor(Zg[g], 16);
        Zg[g] += __shfl_xor(Zg[g], 32);
        Ag[g] += __shfl_xor(Ag[g], 16);
        Ag[g] += __shfl_xor(Ag[g], 32);
    }
    const int r = ks * 4 + wid;            // 0..31
    float Z1 = (lg == 0) ? Zg[0] : (lg == 1) ? Zg[1] : (lg == 2) ? Zg[2] : Zg[3];
    float A1 = (lg == 0) ? Ag[0] : (lg == 1) ? Ag[1] : (lg == 2) ? Ag[2] : Ag[3];
    float Z2 = (lg == 0) ? Zg[4] : (lg == 1) ? Zg[5] : (lg == 2) ? Zg[6] : Zg[7];
    float A2 = (lg == 0) ? Ag[4] : (lg == 1) ? Ag[5] : (lg == 2) ? Ag[6] : Ag[7];
    size_t base = ((size_t)r << 14) + ((size_t)b << 12) + q0;
    P2[base + lg * 16 + ll]       = make_float2(Z1, A1);
    P2[base + (lg + 4) * 16 + ll] = make_float2(Z2, A2);
}

// ---------------------------------------------------------------------------
// Kernel 3: sum 32 additive partials, sigmoid(A/Z + bo)
// ---------------------------------------------------------------------------
__global__ __launch_bounds__(256) void combine_kernel(
    const float2* __restrict__ P2, const float* __restrict__ bo,
    float* __restrict__ out)
{
    int i = blockIdx.x * 256 + threadIdx.x;     // NB*NN = 16384
    float Z = 0.f, A = 0.f;
    #pragma unroll
    for (int r = 0; r < 32; ++r) {
        float2 p = P2[((size_t)r << 14) + i];
        Z += p.x; A += p.y;
    }
    float y = A / Z + bo[0];
    out[i] = 1.f / (1.f + __expf(-y));
}

extern "C" void kernel_launch(void* const* d_in, const int* in_sizes, int n_in,
                              void* d_out, int out_size, void* d_ws, size_t ws_size,
                              hipStream_t stream)
{
    const float* x  = (const float*)d_in[0];
    const float* Wq = (const float*)d_in[1];
    const float* bq = (const float*)d_in[2];
    const float* Wk = (const float*)d_in[3];
    const float* bk = (const float*)d_in[4];
    const float* Wv = (const float*)d_in[5];
    const float* bv = (const float*)d_in[6];
    const float* Wo = (const float*)d_in[7];
    const float* bo = (const float*)d_in[8];
    float* out = (float*)d_out;

    unsigned short* Qb = (unsigned short*)d_ws;            // 2 MB
    unsigned short* Kb = Qb + (size_t)NB * NN * 64;        // 2 MB
    float* VW = (float*)(Kb + (size_t)NB * NN * 64);       // 64 KB
    float2* P2 = (float2*)(VW + (size_t)NB * NN);          // 4 MB

    prep_mfma<<<NB * 64, 256, 0, stream>>>(x, Wq, bq, Wk, bk, Wv, bv, Wo, Qb, Kb, VW);
    attn_mfma<<<NB * 32 * KS, 256, 0, stream>>>(Qb, Kb, VW, P2);
    combine_kernel<<<(NB * NN) / 256, 256, 0, stream>>>(P2, bo, out);
}

// Round 5
// 37.893 us; speedup vs baseline: 8.1702x; 1.0548x over previous
//
#include <hip/hip_runtime.h>
#include <math.h>

#define NB 4
#define NN 4096
#define QSCALE 0.1803368801f   // (1/sqrt(64)) * log2(e): scores in log2 domain

#define KS 8                   // key splits per q-tile
#define KPB 512                // keys per block
#define KPW 128                // keys per wave
#define NTILES 8               // KPW/16
#define NG 4                   // q-groups (16 queries) per wave; q-tile = 64

typedef __bf16 bf16x8 __attribute__((ext_vector_type(8)));
typedef float f32x4 __attribute__((ext_vector_type(4)));

union BF8 { unsigned short u[8]; bf16x8 v; uint4 q; };

static __device__ inline unsigned short f2bf(float f) {
    union { float f; unsigned u; } v; v.f = f;
    unsigned r = v.u + 0x7fffu + ((v.u >> 16) & 1u);   // RNE
    return (unsigned short)(r >> 16);
}

// ---------------------------------------------------------------------------
// Kernel 1 (MFMA prep, 32 positions/block, 512 blocks = 2/CU):
// waves 0,1 -> Q rows (bias+QSCALE), waves 2,3 -> K rows (bias).
// wve = Wo·Wv and cv = Wo·bv computed wave-parallel (shfl reduces).
// VW[b,n] = wve·x[:,n] + cv. One __syncthreads total; epilogue transpose is
// wave-local LDS (no block barrier).
// ---------------------------------------------------------------------------
__global__ __launch_bounds__(256) void prep_mfma(
    const float* __restrict__ x,
    const float* __restrict__ Wq, const float* __restrict__ bq,
    const float* __restrict__ Wk, const float* __restrict__ bk,
    const float* __restrict__ Wv, const float* __restrict__ bv,
    const float* __restrict__ Wo,
    unsigned short* __restrict__ Qb, unsigned short* __restrict__ Kb,
    float* __restrict__ VW)
{
    __shared__ float xt[64 * 33];                 // [c][n], n-pad 33
    __shared__ float wve_s[64];
    __shared__ unsigned short rows[4 * 16 * 72];  // per-wave 16x72 bf16

    const int blk = blockIdx.x;                   // NB*128
    const int b = blk >> 7;
    const int n0 = (blk & 127) << 5;
    const int tid = threadIdx.x;
    const int wid = tid >> 6, lane = tid & 63;
    const int lg = lane >> 4, ll = lane & 15;

    const float* xb = x + (size_t)b * 64 * NN;
    #pragma unroll
    for (int it = 0; it < 8; ++it) {
        int idx = it * 256 + tid;
        int c = idx >> 5, n = idx & 31;
        xt[c * 33 + n] = xb[(size_t)c * NN + n0 + n];
    }
    // wve[c] = sum_e Wo[e]*Wv[e*64+c], 4 lanes per c
    {
        int c = tid >> 2, part = tid & 3;
        float a = 0.f;
        #pragma unroll
        for (int j = 0; j < 16; ++j) {
            int e = part * 16 + j;
            a = fmaf(Wo[e], Wv[e * 64 + c], a);
        }
        a += __shfl_xor(a, 1);
        a += __shfl_xor(a, 2);
        if (part == 0) wve_s[c] = a;
    }
    // cv = Wo·bv via full-wave butterfly (all lanes end with the sum)
    float cv;
    {
        float p = Wo[lane] * bv[lane];
        #pragma unroll
        for (int off = 1; off < 64; off <<= 1) p += __shfl_xor(p, off);
        cv = p;
    }
    __syncthreads();

    // VW: 8 lanes per position
    {
        int nrel = tid >> 3, part = tid & 7;
        float a = 0.f;
        #pragma unroll
        for (int j = 0; j < 8; ++j) {
            int c = part * 8 + j;
            a = fmaf(wve_s[c], xt[c * 33 + nrel], a);
        }
        a += __shfl_xor(a, 1);
        a += __shfl_xor(a, 2);
        a += __shfl_xor(a, 4);
        if (part == 0) VW[(size_t)b * NN + n0 + nrel] = a + cv;
    }

    // A fragments: rows n = (wid&1)*16 + ll
    const int nr = (wid & 1) * 16 + ll;
    BF8 a0, a1;
    #pragma unroll
    for (int j = 0; j < 8; ++j) {
        a0.v[j] = (__bf16)xt[(lg * 8 + j) * 33 + nr];
        a1.v[j] = (__bf16)xt[(32 + lg * 8 + j) * 33 + nr];
    }

    const float* W  = (wid < 2) ? Wq : Wk;
    const float* bs = (wid < 2) ? bq : bk;
    unsigned short* Out = (wid < 2) ? Qb : Kb;
    const float scale = (wid < 2) ? QSCALE : 1.f;
    unsigned short* myrows = rows + wid * (16 * 72);

    #pragma unroll
    for (int ct = 0; ct < 4; ++ct) {
        const float* wr = W + (ct * 16 + ll) * 64;
        float4 f0 = *(const float4*)(wr + lg * 8);
        float4 f1 = *(const float4*)(wr + lg * 8 + 4);
        float4 f2 = *(const float4*)(wr + 32 + lg * 8);
        float4 f3 = *(const float4*)(wr + 32 + lg * 8 + 4);
        BF8 w0, w1;
        w0.v[0] = (__bf16)f0.x; w0.v[1] = (__bf16)f0.y; w0.v[2] = (__bf16)f0.z; w0.v[3] = (__bf16)f0.w;
        w0.v[4] = (__bf16)f1.x; w0.v[5] = (__bf16)f1.y; w0.v[6] = (__bf16)f1.z; w0.v[7] = (__bf16)f1.w;
        w1.v[0] = (__bf16)f2.x; w1.v[1] = (__bf16)f2.y; w1.v[2] = (__bf16)f2.z; w1.v[3] = (__bf16)f2.w;
        w1.v[4] = (__bf16)f3.x; w1.v[5] = (__bf16)f3.y; w1.v[6] = (__bf16)f3.z; w1.v[7] = (__bf16)f3.w;
        f32x4 acc = {0.f, 0.f, 0.f, 0.f};
        acc = __builtin_amdgcn_mfma_f32_16x16x32_bf16(a0.v, w0.v, acc, 0, 0, 0);
        acc = __builtin_amdgcn_mfma_f32_16x16x32_bf16(a1.v, w1.v, acc, 0, 0, 0);
        float bias = bs[ct * 16 + ll];
        #pragma unroll
        for (int r = 0; r < 4; ++r)
            myrows[(lg * 4 + r) * 72 + ct * 16 + ll] = f2bf((acc[r] + bias) * scale);
    }
    // wave-local transpose readback (compiler inserts lgkmcnt waits)
    {
        int n = lane >> 2, c16 = lane & 3;
        const uint4* sp = (const uint4*)&myrows[n * 72 + c16 * 16];
        uint4 v0 = sp[0], v1 = sp[1];
        uint4* dst = (uint4*)(Out + ((size_t)b * NN + n0 + (wid & 1) * 16 + n) * 64 + c16 * 16);
        dst[0] = v0; dst[1] = v1;
    }
}

// ---------------------------------------------------------------------------
// Kernel 2: MFMA attention, no max-tracking (log2-domain scores, bounded).
// Q tile (64 rows) in LDS -> ~45 VGPR -> 8 waves/SIMD; grid 2048 (8 blk/CU).
// Swapped QK^T; per-lane additive (Z,A); 2-way LDS aliasing only (free).
// ---------------------------------------------------------------------------
__global__ __launch_bounds__(256) void attn_mfma(
    const unsigned short* __restrict__ Qb, const unsigned short* __restrict__ Kb,
    const float* __restrict__ VW, float2* __restrict__ P2)
{
    __shared__ unsigned short qlds[64 * 72];   // 64 q-rows x 64 dims, pad 72
    __shared__ float vws[KPB];
    const int blk = blockIdx.x;                // ((b*64 + qt)*KS + ks)
    const int ks = blk & (KS - 1);
    const int t = blk >> 3;
    const int b = t >> 6;
    const int q0 = (t & 63) << 6;
    const int tid = threadIdx.x;
    const int wid = tid >> 6, lane = tid & 63;
    const int lg = lane >> 4, ll = lane & 15;

    {
        const uint4* src = (const uint4*)(Qb + ((size_t)b * NN + q0) * 64);
        #pragma unroll
        for (int k = 0; k < 2; ++k) {
            int idx = tid + k * 256;           // 512 x 16B
            int row = idx >> 3, c8 = idx & 7;
            uint4 v = src[idx];
            *(uint4*)&qlds[row * 72 + c8 * 8] = v;
        }
    }
    for (int i = tid; i < KPB; i += 256)
        vws[i] = VW[(size_t)b * NN + ks * KPB + i];
    __syncthreads();

    const unsigned short* kp =
        Kb + ((size_t)b * NN + ks * KPB + wid * KPW + ll) * 64 + lg * 8;

    float Zg[NG], Ag[NG];
    #pragma unroll
    for (int g = 0; g < NG; ++g) { Zg[g] = 0.f; Ag[g] = 0.f; }

    #pragma unroll
    for (int kt = 0; kt < NTILES; ++kt) {
        const bf16x8 ka0 = *(const bf16x8*)(kp + kt * (16 * 64));
        const bf16x8 ka1 = *(const bf16x8*)(kp + kt * (16 * 64) + 32);
        const float4 vv = *(const float4*)&vws[wid * KPW + kt * 16 + lg * 4];
        #pragma unroll
        for (int g = 0; g < NG; ++g) {
            const bf16x8 qa = *(const bf16x8*)&qlds[(g * 16 + ll) * 72 + lg * 8];
            const bf16x8 qc = *(const bf16x8*)&qlds[(g * 16 + ll) * 72 + 32 + lg * 8];
            f32x4 acc = {0.f, 0.f, 0.f, 0.f};
            acc = __builtin_amdgcn_mfma_f32_16x16x32_bf16(ka0, qa, acc, 0, 0, 0);
            acc = __builtin_amdgcn_mfma_f32_16x16x32_bf16(ka1, qc, acc, 0, 0, 0);
            float e0 = __builtin_amdgcn_exp2f(acc[0]);
            float e1 = __builtin_amdgcn_exp2f(acc[1]);
            float e2 = __builtin_amdgcn_exp2f(acc[2]);
            float e3 = __builtin_amdgcn_exp2f(acc[3]);
            Zg[g] += (e0 + e1) + (e2 + e3);
            Ag[g] += fmaf(e0, vv.x, fmaf(e1, vv.y, fmaf(e2, vv.z, e3 * vv.w)));
        }
    }

    #pragma unroll
    for (int g = 0; g < NG; ++g) {
        Zg[g] += __shfl_xor(Zg[g], 16);
        Zg[g] += __shfl_xor(Zg[g], 32);
        Ag[g] += __shfl_xor(Ag[g], 16);
        Ag[g] += __shfl_xor(Ag[g], 32);
    }
    const int r = ks * 4 + wid;                // 0..31
    float Zo = (lg == 0) ? Zg[0] : (lg == 1) ? Zg[1] : (lg == 2) ? Zg[2] : Zg[3];
    float Ao = (lg == 0) ? Ag[0] : (lg == 1) ? Ag[1] : (lg == 2) ? Ag[2] : Ag[3];
    P2[((size_t)r << 14) + ((size_t)b << 12) + q0 + lane] = make_float2(Zo, Ao);
}

// ---------------------------------------------------------------------------
// Kernel 3: sum 32 additive partials, sigmoid(A/Z + bo). 256 blocks x 64.
// ---------------------------------------------------------------------------
__global__ __launch_bounds__(64) void combine_kernel(
    const float2* __restrict__ P2, const float* __restrict__ bo,
    float* __restrict__ out)
{
    int i = blockIdx.x * 64 + threadIdx.x;     // NB*NN = 16384
    float Z = 0.f, A = 0.f;
    #pragma unroll
    for (int r = 0; r < 32; ++r) {
        float2 p = P2[((size_t)r << 14) + i];
        Z += p.x; A += p.y;
    }
    float y = A / Z + bo[0];
    out[i] = 1.f / (1.f + __expf(-y));
}

extern "C" void kernel_launch(void* const* d_in, const int* in_sizes, int n_in,
                              void* d_out, int out_size, void* d_ws, size_t ws_size,
                              hipStream_t stream)
{
    const float* x  = (const float*)d_in[0];
    const float* Wq = (const float*)d_in[1];
    const float* bq = (const float*)d_in[2];
    const float* Wk = (const float*)d_in[3];
    const float* bk = (const float*)d_in[4];
    const float* Wv = (const float*)d_in[5];
    const float* bv = (const float*)d_in[6];
    const float* Wo = (const float*)d_in[7];
    const float* bo = (const float*)d_in[8];
    float* out = (float*)d_out;

    unsigned short* Qb = (unsigned short*)d_ws;            // 2 MB
    unsigned short* Kb = Qb + (size_t)NB * NN * 64;        // 2 MB
    float* VW = (float*)(Kb + (size_t)NB * NN * 64);       // 64 KB
    float2* P2 = (float2*)(VW + (size_t)NB * NN);          // 4 MB

    prep_mfma<<<NB * 128, 256, 0, stream>>>(x, Wq, bq, Wk, bk, Wv, bv, Wo, Qb, Kb, VW);
    attn_mfma<<<NB * 64 * KS, 256, 0, stream>>>(Qb, Kb, VW, P2);
    combine_kernel<<<(NB * NN) / 64, 64, 0, stream>>>(P2, bo, out);
}